// Round 10
// baseline (266.340 us; speedup 1.0000x reference)
//
#include <hip/hip_runtime.h>
#include <hip/hip_fp16.h>
#include <cstdint>
#include <cstddef>

#define NCLS 50000
#define DIM 512
#define NROW 1024
#define NTN 391   // N-tiles of 128 (ceil(50000/128))
#define NWG 1564  // 4 mt x 391 nt

typedef _Float16 half8 __attribute__((ext_vector_type(8)));
typedef float f32x4 __attribute__((ext_vector_type(4)));

#define AS1(p) ((const __attribute__((address_space(1))) void*)(p))
#define AS3(p) ((__attribute__((address_space(3))) void*)(p))

// ---------------- x: convert to fp16 + row inv-norms (exact f32) ----------------
__global__ void prep_x_kernel(const float* __restrict__ x,
                              __half* __restrict__ xh,
                              float* __restrict__ rn)
{
    int row = blockIdx.x;
    int l = threadIdx.x; // 64 threads = 1 wave
    const float4* xr = (const float4*)(x + (size_t)row * DIM);
    __half2* dst = (__half2*)(xh + (size_t)row * DIM);
    float s = 0.f;
#pragma unroll
    for (int i = 0; i < 2; ++i) {
        int idx = l + i * 64;
        float4 v = xr[idx];
        dst[idx * 2]     = __floats2half2_rn(v.x, v.y);
        dst[idx * 2 + 1] = __floats2half2_rn(v.z, v.w);
        s += v.x * v.x + v.y * v.y + v.z * v.z + v.w * v.w;
    }
#pragma unroll
    for (int off = 32; off > 0; off >>= 1) s += __shfl_down(s, off);
    if (l == 0) rn[row] = rsqrtf(s);
}

// ------- W [512][50000] f32 -> Wt [50000][512] fp16, fused col sum-of-squares ----
__global__ void transpose_w_kernel(const float* __restrict__ W,
                                   __half* __restrict__ Wt,
                                   float* __restrict__ part)
{
    __shared__ float tile[64][65];
    __shared__ float cpart[4][64];
    int n0 = blockIdx.x * 64;
    int k0 = blockIdx.y * 64;
    int t = threadIdx.x; // 256
    int f4 = t & 15;
    int kr = t >> 4;
    int n = n0 + f4 * 4;
    bool ok = (n < NCLS);
#pragma unroll
    for (int i = 0; i < 4; ++i) {
        int k = kr + i * 16;
        float4 v = ok ? *(const float4*)(W + (size_t)(k0 + k) * NCLS + n)
                      : make_float4(0.f, 0.f, 0.f, 0.f);
        tile[k][f4 * 4 + 0] = v.x;
        tile[k][f4 * 4 + 1] = v.y;
        tile[k][f4 * 4 + 2] = v.z;
        tile[k][f4 * 4 + 3] = v.w;
    }
    __syncthreads();
#pragma unroll
    for (int i = 0; i < 8; ++i) {
        int idx = t + i * 256;
        int nn = idx >> 5;
        int kp = idx & 31;
        int gn = n0 + nn;
        if (gn < NCLS) {
            __half2 h = __floats2half2_rn(tile[kp * 2][nn], tile[kp * 2 + 1][nn]);
            *(__half2*)(Wt + (size_t)gn * DIM + k0 + kp * 2) = h;
        }
    }
    {
        int nn = t & 63;
        int seg = t >> 6;
        float s = 0.f;
#pragma unroll
        for (int k = 0; k < 16; ++k) {
            float v = tile[seg * 16 + k][nn];
            s += v * v;
        }
        cpart[seg][nn] = s;
        __syncthreads();
        if (t < 64 && n0 + t < NCLS) {
            part[(size_t)blockIdx.y * NCLS + n0 + t] =
                cpart[0][t] + cpart[1][t] + cpart[2][t] + cpart[3][t];
        }
    }
}

__global__ void make_cn_kernel(const float* __restrict__ part, float* __restrict__ cn)
{
    int c = blockIdx.x * 256 + threadIdx.x;
    if (c >= NCLS) return;
    float s = 0.f;
#pragma unroll
    for (int j = 0; j < 8; ++j) s += part[(size_t)j * NCLS + c];
    cn[c] = rsqrtf(s);
}

// ---------------- labels from one-hot y (streaming, coalesced) -------------------
__global__ void find_labels_kernel(const float4* __restrict__ y4, int* __restrict__ lab)
{
    int i4 = blockIdx.x * 256 + threadIdx.x; // exactly 12,800,000 threads
    float4 v = y4[i4];
    if (v.x != 0.f || v.y != 0.f || v.z != 0.f || v.w != 0.f) {
        long base = (long)i4 * 4;
        if (v.x != 0.f) { long i = base + 0; lab[i / NCLS] = (int)(i % NCLS); }
        if (v.y != 0.f) { long i = base + 1; lab[i / NCLS] = (int)(i % NCLS); }
        if (v.z != 0.f) { long i = base + 2; lab[i / NCLS] = (int)(i % NCLS); }
        if (v.w != 0.f) { long i = base + 3; lab[i / NCLS] = (int)(i % NCLS); }
    }
}

// ---------------- GEMM + arcface + exp, two-pass ---------------------------------
// BM=256, BN=128, BK=64. 512 threads, 8 waves (4M x 2N), 64x64 per wave.
// Single-buffer m97 loop (stage->sync->compute->sync), 2 blocks/CU, XOR swizzle.
// Halves B-staging vs 128x128 (4 m-tiles instead of 8 re-stage Wt).
// PASS 0: margin via lab[]; writes rowpart sums only.
// PASS 1: margin via lab[]; e*rs stores repacked through LDS -> float4.
template<int PASS>
__global__ __launch_bounds__(512, 4) void gemm_arc_kernel(
    const __half* __restrict__ A,
    const __half* __restrict__ Bt,
    const float* __restrict__ rn,
    const float* __restrict__ cn,
    const int* __restrict__ lab,
    const float* __restrict__ rs,
    float* __restrict__ out,
    float* __restrict__ rowpart)
{
    __shared__ __align__(16) __half As[256 * 64];   // 32 KB
    __shared__ __align__(16) __half Bs[128 * 64];   // 16 KB
    __shared__ float rsum[2][256];                  // 2 KB

    const int tid = threadIdx.x;
    const int wid = tid >> 6;
    const int lane = tid & 63;
    const int wm = wid >> 1;   // 0..3
    const int wn = wid & 1;    // 0..1
    const int rl = lane & 15;
    const int krow = lane >> 4; // 0..3

    // bijective XCD swizzle (m204): NWG = 1564 = 8*195 + 4; M-fastest (4 mt/nt)
    const int orig = blockIdx.x;
    const int xcd = orig & 7;
    const int q = NWG >> 3, r8 = NWG & 7;                 // 195, 4
    const int base_w = (xcd < r8) ? xcd * (q + 1) : r8 * (q + 1) + (xcd - r8) * q;
    const int w = base_w + (orig >> 3);
    const int mt = w & 3;
    const int nt = w >> 2;
    const int tileM = mt * 256;
    const int tileN = nt * 128;

    f32x4 acc[4][4] = {};

    // staging: thread -> row-group r=tid>>3 (0..63), 16B pos p=tid&7.
    // Swizzle involution: data k-block kb of row R lives at pos kb^(R&7).
    const int srr = tid >> 3;                     // 0..63
    const int sblk = (tid & 7) ^ (srr & 7);       // pre-swizzled src 16B-block
    auto stage = [&](int k0) {
#pragma unroll
        for (int c = 0; c < 4; ++c) {             // A: 256 rows = 4 x 64
            const __half* sa = A + (size_t)(tileM + c * 64 + srr) * DIM + k0 + sblk * 8;
            __builtin_amdgcn_global_load_lds(AS1(sa), AS3((char*)As + c * 8192 + tid * 16), 16, 0, 0);
        }
#pragma unroll
        for (int c = 0; c < 2; ++c) {             // B: 128 rows = 2 x 64
            int gn = tileN + c * 64 + srr;
            if (gn > NCLS - 1) gn = NCLS - 1;     // clamp N edge (masked later)
            const __half* sb = Bt + (size_t)gn * DIM + k0 + sblk * 8;
            __builtin_amdgcn_global_load_lds(AS1(sb), AS3((char*)Bs + c * 8192 + tid * 16), 16, 0, 0);
        }
    };

    auto compute = [&]() {
#pragma unroll
        for (int kk = 0; kk < 2; ++kk) {
            half8 af[4], bf[4];
#pragma unroll
            for (int m = 0; m < 4; ++m) {
                int row = wm * 64 + m * 16 + rl;           // 0..255
                int kb = (kk * 4 + krow) ^ (row & 7);      // XOR de-swizzle
                af[m] = *(const half8*)((const char*)As + row * 128 + kb * 16);
            }
#pragma unroll
            for (int n = 0; n < 4; ++n) {
                int row = wn * 64 + n * 16 + rl;           // 0..127
                int kb = (kk * 4 + krow) ^ (row & 7);
                bf[n] = *(const half8*)((const char*)Bs + row * 128 + kb * 16);
            }
#pragma unroll
            for (int m = 0; m < 4; ++m)
#pragma unroll
                for (int n = 0; n < 4; ++n)
                    acc[m][n] = __builtin_amdgcn_mfma_f32_16x16x32_f16(af[m], bf[n], acc[m][n], 0, 0, 0);
        }
    };

#pragma unroll 1
    for (int k0 = 0; k0 < DIM; k0 += 64) {
        stage(k0);
        __syncthreads();
        compute();
        __syncthreads();
    }

    // epilogue
    const float cosM = 0.8775825618903728f;
    const float sinM = 0.4794255386042030f;
    const int col_l = rl;
    const int rgrp = krow;
    float* buf = (float*)As;   // PASS 1 repack buffer [64][128] f32 (32 KB)

#pragma unroll
    for (int m = 0; m < 4; ++m) {
        int lr0 = wm * 64 + m * 16 + rgrp * 4;   // local row base 0..255
        int gr0 = tileM + lr0;
        float rnv[4]; int labv[4]; float rsv[4];
#pragma unroll
        for (int r = 0; r < 4; ++r) {
            rnv[r] = rn[gr0 + r];
            labv[r] = lab[gr0 + r];
            if (PASS == 1) rsv[r] = rs[gr0 + r];
        }
        float rowacc[4] = {0.f, 0.f, 0.f, 0.f};
#pragma unroll
        for (int n = 0; n < 4; ++n) {
            int gc = tileN + wn * 64 + n * 16 + col_l;
            bool okc = (gc < NCLS);
            float cnv = okc ? cn[gc] : 0.f;
#pragma unroll
            for (int r = 0; r < 4; ++r) {
                float cv = acc[m][n][r] * rnv[r] * cnv;
                float logit;
                if (gc == labv[r]) {
                    float cc = fminf(fmaxf(cv, -1.f + 1e-7f), 1.f - 1e-7f);
                    logit = 64.f * (cc * cosM - sqrtf(1.f - cc * cc) * sinM);
                } else {
                    logit = 64.f * cv;
                }
                float e = __expf(logit);
                if (PASS == 0) {
                    if (okc) rowacc[r] += e;
                } else {
                    // buf row = wm*16 + rgrp*4 + r (0..63), col = wn*64+n*16+col_l
                    buf[(wm * 16 + rgrp * 4 + r) * 128 + wn * 64 + n * 16 + col_l] = e * rsv[r];
                }
            }
        }
        if (PASS == 0) {
#pragma unroll
            for (int r = 0; r < 4; ++r) {
                float s = rowacc[r];
                s += __shfl_xor(s, 1);
                s += __shfl_xor(s, 2);
                s += __shfl_xor(s, 4);
                s += __shfl_xor(s, 8);
                if (col_l == 0) rsum[wn][lr0 + r] = s;
            }
        } else {
            __syncthreads();   // buf slab (64 rows x 128 cols) complete
#pragma unroll
            for (int i = 0; i < 4; ++i) {
                int idx = tid + i * 512;          // 0..2047
                int lr = idx >> 5;                // 0..63
                int c4 = idx & 31;
                int gr = tileM + (lr >> 4) * 64 + m * 16 + (lr & 15);
                int gcl = tileN + c4 * 4;
                if (gcl < NCLS)
                    *(float4*)(out + (size_t)gr * NCLS + gcl) = ((float4*)buf)[idx];
            }
            __syncthreads();   // before next m overwrites buf
        }
    }
    if (PASS == 0) {
        __syncthreads();
        if (tid < 256) {
            float tot = rsum[0][tid] + rsum[1][tid];
            rowpart[(size_t)nt * NROW + tileM + tid] = tot;
        }
    }
}

// ---------------- reduce per-tile row sums -> 1/rowsum ---------------------------
__global__ void reduce_rs_kernel(const float* __restrict__ rowpart, float* __restrict__ rs)
{
    int row = blockIdx.x * 256 + threadIdx.x; // 4 x 256 = 1024
    float s = 0.f;
    for (int t = 0; t < NTN; ++t) s += rowpart[(size_t)t * NROW + row];
    rs[row] = 1.f / s;
}

extern "C" void kernel_launch(void* const* d_in, const int* in_sizes, int n_in,
                              void* d_out, int out_size, void* d_ws, size_t ws_size,
                              hipStream_t stream)
{
    const float* x = (const float*)d_in[0]; // [1024][512]
    const float* y = (const float*)d_in[1]; // [1024][50000] one-hot
    const float* W = (const float*)d_in[2]; // [512][50000]
    float* out = (float*)d_out;             // [1024][50000]

    char* ws = (char*)d_ws;
    __half* Wt     = (__half*)(ws);               // 51,200,000 B : W^T fp16 [50000][512]
    __half* xh     = (__half*)(ws + 51200000);    //  1,048,576 B : x fp16
    float* rn      = (float*) (ws + 52248576);    //      4,096 B : row inv-norms
    float* cn      = (float*) (ws + 52252672);    //    200,000 B : col inv-norms
    // part [8][50000] (consumed by make_cn) then reused as rowpart [391][1024]
    float* part    = (float*) (ws + 52452672);    //  1,601,536 B : union(part, rowpart)
    float* rowpart = part;
    int*   lab     = (int*)   (ws + 54054208);    //      4,096 B : labels
    float* rs      = (float*) (ws + 54058304);    //      4,096 B : 1/rowsum

    hipLaunchKernelGGL(prep_x_kernel, dim3(NROW), dim3(64), 0, stream, x, xh, rn);
    hipLaunchKernelGGL(transpose_w_kernel, dim3(782, 8), dim3(256), 0, stream, W, Wt, part);
    hipLaunchKernelGGL(make_cn_kernel, dim3(196), dim3(256), 0, stream, part, cn);
    hipLaunchKernelGGL(find_labels_kernel, dim3(50000), dim3(256), 0, stream, (const float4*)y, lab);
    hipLaunchKernelGGL(gemm_arc_kernel<0>, dim3(NWG), dim3(512), 0, stream,
                       xh, Wt, rn, cn, lab, rs, out, rowpart);
    hipLaunchKernelGGL(reduce_rs_kernel, dim3(4), dim3(256), 0, stream, rowpart, rs);
    hipLaunchKernelGGL(gemm_arc_kernel<1>, dim3(NWG), dim3(512), 0, stream,
                       xh, Wt, rn, cn, lab, rs, out, rowpart);
}

// Round 11
// 265.876 us; speedup vs baseline: 1.0017x; 1.0017x over previous
//
#include <hip/hip_runtime.h>
#include <hip/hip_fp16.h>
#include <cstdint>
#include <cstddef>

#define NCLS 50000
#define DIM 512
#define NROW 1024
#define NTN 391   // ceil(50000/128)

typedef _Float16 half8 __attribute__((ext_vector_type(8)));
typedef float f32x4 __attribute__((ext_vector_type(4)));

#define AS1(p) ((const __attribute__((address_space(1))) void*)(p))
#define AS3(p) ((__attribute__((address_space(3))) void*)(p))

// ---------------- x: convert to fp16 + row inv-norms (exact f32) ----------------
__global__ void prep_x_kernel(const float* __restrict__ x,
                              __half* __restrict__ xh,
                              float* __restrict__ rn)
{
    int row = blockIdx.x;
    int l = threadIdx.x; // 64 threads = 1 wave
    const float4* xr = (const float4*)(x + (size_t)row * DIM);
    __half2* dst = (__half2*)(xh + (size_t)row * DIM);
    float s = 0.f;
#pragma unroll
    for (int i = 0; i < 2; ++i) {
        int idx = l + i * 64;
        float4 v = xr[idx];
        dst[idx * 2]     = __floats2half2_rn(v.x, v.y);
        dst[idx * 2 + 1] = __floats2half2_rn(v.z, v.w);
        s += v.x * v.x + v.y * v.y + v.z * v.z + v.w * v.w;
    }
#pragma unroll
    for (int off = 32; off > 0; off >>= 1) s += __shfl_down(s, off);
    if (l == 0) rn[row] = rsqrtf(s);
}

// ------- W [512][50000] f32 -> Wt [50000][512] fp16, fused col sum-of-squares ----
__global__ void transpose_w_kernel(const float* __restrict__ W,
                                   __half* __restrict__ Wt,
                                   float* __restrict__ part)
{
    __shared__ float tile[64][65];
    __shared__ float cpart[4][64];
    int n0 = blockIdx.x * 64;
    int k0 = blockIdx.y * 64;
    int t = threadIdx.x; // 256
    int f4 = t & 15;
    int kr = t >> 4;
    int n = n0 + f4 * 4;
    bool ok = (n < NCLS);
#pragma unroll
    for (int i = 0; i < 4; ++i) {
        int k = kr + i * 16;
        float4 v = ok ? *(const float4*)(W + (size_t)(k0 + k) * NCLS + n)
                      : make_float4(0.f, 0.f, 0.f, 0.f);
        tile[k][f4 * 4 + 0] = v.x;
        tile[k][f4 * 4 + 1] = v.y;
        tile[k][f4 * 4 + 2] = v.z;
        tile[k][f4 * 4 + 3] = v.w;
    }
    __syncthreads();
#pragma unroll
    for (int i = 0; i < 8; ++i) {
        int idx = t + i * 256;
        int nn = idx >> 5;
        int kp = idx & 31;
        int gn = n0 + nn;
        if (gn < NCLS) {
            __half2 h = __floats2half2_rn(tile[kp * 2][nn], tile[kp * 2 + 1][nn]);
            *(__half2*)(Wt + (size_t)gn * DIM + k0 + kp * 2) = h;
        }
    }
    {
        int nn = t & 63;
        int seg = t >> 6;
        float s = 0.f;
#pragma unroll
        for (int k = 0; k < 16; ++k) {
            float v = tile[seg * 16 + k][nn];
            s += v * v;
        }
        cpart[seg][nn] = s;
        __syncthreads();
        if (t < 64 && n0 + t < NCLS) {
            part[(size_t)blockIdx.y * NCLS + n0 + t] =
                cpart[0][t] + cpart[1][t] + cpart[2][t] + cpart[3][t];
        }
    }
}

__global__ void make_cn_kernel(const float* __restrict__ part, float* __restrict__ cn)
{
    int c = blockIdx.x * 256 + threadIdx.x;
    if (c >= NCLS) return;
    float s = 0.f;
#pragma unroll
    for (int j = 0; j < 8; ++j) s += part[(size_t)j * NCLS + c];
    cn[c] = rsqrtf(s);
}

// ---------------- labels from one-hot y (streaming, coalesced) -------------------
__global__ void find_labels_kernel(const float4* __restrict__ y4, int* __restrict__ lab)
{
    int i4 = blockIdx.x * 256 + threadIdx.x; // exactly 12,800,000 threads
    float4 v = y4[i4];
    if (v.x != 0.f || v.y != 0.f || v.z != 0.f || v.w != 0.f) {
        long base = (long)i4 * 4;
        if (v.x != 0.f) { long i = base + 0; lab[i / NCLS] = (int)(i % NCLS); }
        if (v.y != 0.f) { long i = base + 1; lab[i / NCLS] = (int)(i % NCLS); }
        if (v.z != 0.f) { long i = base + 2; lab[i / NCLS] = (int)(i % NCLS); }
        if (v.w != 0.f) { long i = base + 3; lab[i / NCLS] = (int)(i % NCLS); }
    }
}

// ---------------- GEMM + arcface + exp, two-pass ---------------------------------
// 128x128 tile, 4 waves (2x2), K split into 16 half-tiles (BK=32, 16 KB/slot).
// 2-slot LDS double-buffer (32 KB total -> SAME 4 blocks/CU as r9) + counted
// vmcnt(4): tile h's loads issued one full iteration before their wait. Fresh
// loads never drained. Swizzle for 64 B rows: block p of row R at p^(R&3).
// PASS 0: margin via lab[]; rowpart sums only. PASS 1: e*rs via LDS repack.
template<int PASS>
__global__ __launch_bounds__(256, 4) void gemm_arc_kernel(
    const __half* __restrict__ A,
    const __half* __restrict__ Bt,
    const float* __restrict__ rn,
    const float* __restrict__ cn,
    const int* __restrict__ lab,
    const float* __restrict__ rs,
    float* __restrict__ out,
    float* __restrict__ rowpart)
{
    __shared__ __align__(16) char ring[2][16384];   // per slot: A 8 KB + B 8 KB
    __shared__ float rsum[2][128];

    const int tid = threadIdx.x;
    const int wid = tid >> 6;
    const int lane = tid & 63;
    const int wm = wid >> 1;
    const int wn = wid & 1;
    const int rl = lane & 15;
    const int krow = lane >> 4;                    // 0..3
    const int koff = (krow ^ (rl & 3)) * 16;       // de-swizzled 16B k-block (lane-const)

    // bijective XCD swizzle: 3128 = 8 * 391; M-fastest (8 mt per nt) for Bt reuse
    const int b = blockIdx.x;
    const int w = (b & 7) * NTN + (b >> 3);
    const int mt = w & 7;
    const int nt = w >> 3;
    const int tileM = mt * 128;
    const int tileN = nt * 128;

    f32x4 acc[4][4] = {};

    // staging: 2 calls for A (4 KB each) + 2 for B. Cell index = c*256+tid;
    // row = cell>>2 (0..127), p = cell&3; global block = p ^ (row&3).
    const int row0 = tid >> 2;           // rows for c=0 (0..63)
    const int row1 = row0 + 64;          // rows for c=1 (64..127)
    const int p0 = (tid & 3) ^ (row0 & 3);
    const int p1 = (tid & 3) ^ (row1 & 3);
    const __half* aS0 = A + (size_t)(tileM + row0) * DIM + p0 * 8;
    const __half* aS1 = A + (size_t)(tileM + row1) * DIM + p1 * 8;
    int gn0 = tileN + row0; if (gn0 > NCLS - 1) gn0 = NCLS - 1;
    int gn1 = tileN + row1; if (gn1 > NCLS - 1) gn1 = NCLS - 1;
    const __half* bS0 = Bt + (size_t)gn0 * DIM + p0 * 8;
    const __half* bS1 = Bt + (size_t)gn1 * DIM + p1 * 8;
    const int ldsBase = wid * 1024;      // wave-uniform; HW adds lane*16

    auto stage = [&](int h) {
        char* s = ring[h & 1];
        const int ko = h * 32;
        __builtin_amdgcn_global_load_lds(AS1(aS0 + ko), AS3(s + ldsBase), 16, 0, 0);
        __builtin_amdgcn_global_load_lds(AS1(aS1 + ko), AS3(s + 4096 + ldsBase), 16, 0, 0);
        __builtin_amdgcn_global_load_lds(AS1(bS0 + ko), AS3(s + 8192 + ldsBase), 16, 0, 0);
        __builtin_amdgcn_global_load_lds(AS1(bS1 + ko), AS3(s + 12288 + ldsBase), 16, 0, 0);
    };

    stage(0);   // 4 loads/thread in flight

#pragma unroll 1
    for (int h = 0; h < 16; ++h) {
        __builtin_amdgcn_s_barrier();           // prev readers of slot h+1's buffer done
        if (h < 15) {
            stage(h + 1);                       // fills other slot; stays in flight
            asm volatile("s_waitcnt vmcnt(4)" ::: "memory");   // tile h resident
        } else {
            asm volatile("s_waitcnt vmcnt(0)" ::: "memory");
        }
        __builtin_amdgcn_s_barrier();           // all waves certified tile h
        __builtin_amdgcn_sched_barrier(0);

        const char* s = ring[h & 1];
        half8 af[4], bf[4];
#pragma unroll
        for (int m = 0; m < 4; ++m)
            af[m] = *(const half8*)(s + (wm * 64 + m * 16 + rl) * 64 + koff);
#pragma unroll
        for (int n = 0; n < 4; ++n)
            bf[n] = *(const half8*)(s + 8192 + (wn * 64 + n * 16 + rl) * 64 + koff);
        __builtin_amdgcn_s_setprio(1);
#pragma unroll
        for (int m = 0; m < 4; ++m)
#pragma unroll
            for (int n = 0; n < 4; ++n)
                acc[m][n] = __builtin_amdgcn_mfma_f32_16x16x32_f16(af[m], bf[n], acc[m][n], 0, 0, 0);
        __builtin_amdgcn_s_setprio(0);
    }
    __syncthreads();   // before LDS reuse in epilogue

    // epilogue (r9-proven)
    const float cosM = 0.8775825618903728f;
    const float sinM = 0.4794255386042030f;
    const int col_l = rl;
    const int rgrp = krow;
    float* buf = (float*)ring;   // PASS 1 repack buffer [32][128] f32 (16 KB)

#pragma unroll
    for (int m = 0; m < 4; ++m) {
        int lr0 = wm * 64 + m * 16 + rgrp * 4;   // local row base 0..127
        int gr0 = tileM + lr0;
        float rnv[4]; int labv[4]; float rsv[4];
#pragma unroll
        for (int r = 0; r < 4; ++r) {
            rnv[r] = rn[gr0 + r];
            labv[r] = lab[gr0 + r];
            if (PASS == 1) rsv[r] = rs[gr0 + r];
        }
        float rowacc[4] = {0.f, 0.f, 0.f, 0.f};
#pragma unroll
        for (int n = 0; n < 4; ++n) {
            int gc = tileN + wn * 64 + n * 16 + col_l;
            bool okc = (gc < NCLS);
            float cnv = okc ? cn[gc] : 0.f;
#pragma unroll
            for (int r = 0; r < 4; ++r) {
                float cv = acc[m][n][r] * rnv[r] * cnv;
                float logit;
                if (gc == labv[r]) {
                    float cc = fminf(fmaxf(cv, -1.f + 1e-7f), 1.f - 1e-7f);
                    logit = 64.f * (cc * cosM - sqrtf(1.f - cc * cc) * sinM);
                } else {
                    logit = 64.f * cv;
                }
                float e = __expf(logit);
                if (PASS == 0) {
                    if (okc) rowacc[r] += e;
                } else {
                    buf[(wm * 16 + rgrp * 4 + r) * 128 + wn * 64 + n * 16 + col_l] = e * rsv[r];
                }
            }
        }
        if (PASS == 0) {
#pragma unroll
            for (int r = 0; r < 4; ++r) {
                float s = rowacc[r];
                s += __shfl_xor(s, 1);
                s += __shfl_xor(s, 2);
                s += __shfl_xor(s, 4);
                s += __shfl_xor(s, 8);
                if (col_l == 0) rsum[wn][lr0 + r] = s;
            }
        } else {
            __syncthreads();   // buf slab complete
#pragma unroll
            for (int i = 0; i < 4; ++i) {
                int idx = tid + i * 256;          // 0..1023
                int lr = idx >> 5;                // 0..31
                int c4 = idx & 31;
                int gr = tileM + (lr >> 4) * 64 + m * 16 + (lr & 15);
                int gcl = tileN + c4 * 4;
                if (gcl < NCLS)
                    *(float4*)(out + (size_t)gr * NCLS + gcl) = ((float4*)buf)[idx];
            }
            __syncthreads();   // before next m overwrites buf
        }
    }
    if (PASS == 0) {
        __syncthreads();
        if (tid < 128) {
            float tot = rsum[0][tid] + rsum[1][tid];
            rowpart[(size_t)nt * NROW + tileM + tid] = tot;
        }
    }
}

// ---------------- reduce per-tile row sums -> 1/rowsum ---------------------------
__global__ void reduce_rs_kernel(const float* __restrict__ rowpart, float* __restrict__ rs)
{
    int row = blockIdx.x * 256 + threadIdx.x; // 4 x 256 = 1024
    float s = 0.f;
    for (int t = 0; t < NTN; ++t) s += rowpart[(size_t)t * NROW + row];
    rs[row] = 1.f / s;
}

extern "C" void kernel_launch(void* const* d_in, const int* in_sizes, int n_in,
                              void* d_out, int out_size, void* d_ws, size_t ws_size,
                              hipStream_t stream)
{
    const float* x = (const float*)d_in[0]; // [1024][512]
    const float* y = (const float*)d_in[1]; // [1024][50000] one-hot
    const float* W = (const float*)d_in[2]; // [512][50000]
    float* out = (float*)d_out;             // [1024][50000]

    char* ws = (char*)d_ws;
    __half* Wt     = (__half*)(ws);               // 51,200,000 B : W^T fp16 [50000][512]
    __half* xh     = (__half*)(ws + 51200000);    //  1,048,576 B : x fp16
    float* rn      = (float*) (ws + 52248576);    //      4,096 B : row inv-norms
    float* cn      = (float*) (ws + 52252672);    //    200,000 B : col inv-norms
    // part [8][50000] (consumed by make_cn) then reused as rowpart [391][1024]
    float* part    = (float*) (ws + 52452672);    //  1,601,536 B : union(part, rowpart)
    float* rowpart = part;
    int*   lab     = (int*)   (ws + 54054208);    //      4,096 B : labels
    float* rs      = (float*) (ws + 54058304);    //      4,096 B : 1/rowsum

    hipLaunchKernelGGL(prep_x_kernel, dim3(NROW), dim3(64), 0, stream, x, xh, rn);
    hipLaunchKernelGGL(transpose_w_kernel, dim3(782, 8), dim3(256), 0, stream, W, Wt, part);
    hipLaunchKernelGGL(make_cn_kernel, dim3(196), dim3(256), 0, stream, part, cn);
    hipLaunchKernelGGL(find_labels_kernel, dim3(50000), dim3(256), 0, stream, (const float4*)y, lab);
    hipLaunchKernelGGL(gemm_arc_kernel<0>, dim3(8 * NTN), dim3(256), 0, stream,
                       xh, Wt, rn, cn, lab, rs, out, rowpart);
    hipLaunchKernelGGL(reduce_rs_kernel, dim3(4), dim3(256), 0, stream, rowpart, rs);
    hipLaunchKernelGGL(gemm_arc_kernel<1>, dim3(8 * NTN), dim3(256), 0, stream,
                       xh, Wt, rn, cn, lab, rs, out, rowpart);
}

// Round 12
// 252.977 us; speedup vs baseline: 1.0528x; 1.0510x over previous
//
#include <hip/hip_runtime.h>
#include <hip/hip_fp16.h>
#include <cstdint>
#include <cstddef>

#define NCLS 50000
#define DIM 512
#define NROW 1024
#define NTN 391   // ceil(50000/128)

typedef _Float16 half8 __attribute__((ext_vector_type(8)));
typedef float f32x4 __attribute__((ext_vector_type(4)));

#define AS1(p) ((const __attribute__((address_space(1))) void*)(p))
#define AS3(p) ((__attribute__((address_space(3))) void*)(p))

// ---------------- x: convert to fp16 + row inv-norms (exact f32) ----------------
__global__ void prep_x_kernel(const float* __restrict__ x,
                              __half* __restrict__ xh,
                              float* __restrict__ rn)
{
    int row = blockIdx.x;
    int l = threadIdx.x; // 64 threads = 1 wave
    const float4* xr = (const float4*)(x + (size_t)row * DIM);
    __half2* dst = (__half2*)(xh + (size_t)row * DIM);
    float s = 0.f;
#pragma unroll
    for (int i = 0; i < 2; ++i) {
        int idx = l + i * 64;
        float4 v = xr[idx];
        dst[idx * 2]     = __floats2half2_rn(v.x, v.y);
        dst[idx * 2 + 1] = __floats2half2_rn(v.z, v.w);
        s += v.x * v.x + v.y * v.y + v.z * v.z + v.w * v.w;
    }
#pragma unroll
    for (int off = 32; off > 0; off >>= 1) s += __shfl_down(s, off);
    if (l == 0) rn[row] = rsqrtf(s);
}

// ---- fused: W transpose+fp16 (+col sumsq partials)  ||  label scan of y --------
// Blocks 0..6255: transpose body (782 n-tiles x 8 k-tiles).
// Blocks 6256..8303: grid-stride one-hot scan (2048 virtual blocks).
// Both memory-bound streams share the BW window instead of serializing.
__global__ void prep_w_labels_kernel(const float* __restrict__ W,
                                     __half* __restrict__ Wt,
                                     float* __restrict__ part,
                                     const float4* __restrict__ y4,
                                     int* __restrict__ lab)
{
    __shared__ float tile[64][65];
    __shared__ float cpart[4][64];

    const int t = threadIdx.x; // 256
    if (blockIdx.x < 6256) {
        const int bx = blockIdx.x % 782;   // n-tile
        const int by = blockIdx.x / 782;   // k-tile 0..7
        int n0 = bx * 64;
        int k0 = by * 64;
        int f4 = t & 15;
        int kr = t >> 4;
        int n = n0 + f4 * 4;
        bool ok = (n < NCLS);
#pragma unroll
        for (int i = 0; i < 4; ++i) {
            int k = kr + i * 16;
            float4 v = ok ? *(const float4*)(W + (size_t)(k0 + k) * NCLS + n)
                          : make_float4(0.f, 0.f, 0.f, 0.f);
            tile[k][f4 * 4 + 0] = v.x;
            tile[k][f4 * 4 + 1] = v.y;
            tile[k][f4 * 4 + 2] = v.z;
            tile[k][f4 * 4 + 3] = v.w;
        }
        __syncthreads();
#pragma unroll
        for (int i = 0; i < 8; ++i) {
            int idx = t + i * 256;
            int nn = idx >> 5;
            int kp = idx & 31;
            int gn = n0 + nn;
            if (gn < NCLS) {
                __half2 h = __floats2half2_rn(tile[kp * 2][nn], tile[kp * 2 + 1][nn]);
                *(__half2*)(Wt + (size_t)gn * DIM + k0 + kp * 2) = h;
            }
        }
        {
            int nn = t & 63;
            int seg = t >> 6;
            float s = 0.f;
#pragma unroll
            for (int k = 0; k < 16; ++k) {
                float v = tile[seg * 16 + k][nn];
                s += v * v;
            }
            cpart[seg][nn] = s;
            __syncthreads();
            if (t < 64 && n0 + t < NCLS) {
                part[(size_t)by * NCLS + n0 + t] =
                    cpart[0][t] + cpart[1][t] + cpart[2][t] + cpart[3][t];
            }
        }
    } else {
        // grid-stride label scan: 2048 vblocks x 256 threads over 12.8M float4
        const int vb = blockIdx.x - 6256;
        for (int i4 = vb * 256 + t; i4 < 12800000; i4 += 2048 * 256) {
            float4 v = y4[i4];
            if (v.x != 0.f || v.y != 0.f || v.z != 0.f || v.w != 0.f) {
                long base = (long)i4 * 4;
                if (v.x != 0.f) { long i = base + 0; lab[i / NCLS] = (int)(i % NCLS); }
                if (v.y != 0.f) { long i = base + 1; lab[i / NCLS] = (int)(i % NCLS); }
                if (v.z != 0.f) { long i = base + 2; lab[i / NCLS] = (int)(i % NCLS); }
                if (v.w != 0.f) { long i = base + 3; lab[i / NCLS] = (int)(i % NCLS); }
            }
        }
    }
}

__global__ void make_cn_kernel(const float* __restrict__ part, float* __restrict__ cn)
{
    int c = blockIdx.x * 256 + threadIdx.x;
    if (c >= NCLS) return;
    float s = 0.f;
#pragma unroll
    for (int j = 0; j < 8; ++j) s += part[(size_t)j * NCLS + c];
    cn[c] = rsqrtf(s);
}

// ---------------- GEMM + arcface + exp, two-pass (r9 champion, verbatim) ---------
// m97 structure: 128x128 tile, BK=64, 4 waves (2x2), single 32 KB LDS buffer,
// stage->sync->compute->sync, 4 blocks/CU.
// PASS 0: margin via lab[]; writes rowpart sums only.
// PASS 1: margin via lab[]; e*rs stores repacked through LDS -> float4.
template<int PASS>
__global__ __launch_bounds__(256, 4) void gemm_arc_kernel(
    const __half* __restrict__ A,
    const __half* __restrict__ Bt,
    const float* __restrict__ rn,
    const float* __restrict__ cn,
    const int* __restrict__ lab,
    const float* __restrict__ rs,
    float* __restrict__ out,
    float* __restrict__ rowpart)
{
    __shared__ __align__(16) __half As[128 * 64];
    __shared__ __align__(16) __half Bs[128 * 64];
    __shared__ float rsum[2][128];

    const int tid = threadIdx.x;
    const int wid = tid >> 6;
    const int lane = tid & 63;
    const int wm = wid >> 1;
    const int wn = wid & 1;

    // bijective XCD swizzle: 3128 = 8 * 391; M-fastest (8 mt per nt) for Bt reuse
    const int b = blockIdx.x;
    const int w = (b & 7) * NTN + (b >> 3);
    const int mt = w & 7;
    const int nt = w >> 3;
    const int tileM = mt * 128;
    const int tileN = nt * 128;

    const int srow = lane >> 3;            // 0..7
    const int sblk = (lane & 7) ^ srow;    // pre-swizzled global 16B-block

    f32x4 acc[4][4] = {};

    auto stage = [&](int k0) {
#pragma unroll
        for (int c = 0; c < 4; ++c) {
            int chunk = wid * 4 + c;       // wave-uniform
            int row = chunk * 8 + srow;    // 0..127
            const __half* sa = A + (size_t)(tileM + row) * DIM + k0 + sblk * 8;
            __builtin_amdgcn_global_load_lds(AS1(sa), AS3((char*)As + chunk * 1024), 16, 0, 0);
            int gn = tileN + row;
            if (gn > NCLS - 1) gn = NCLS - 1; // clamp N edge (masked later)
            const __half* sb = Bt + (size_t)gn * DIM + k0 + sblk * 8;
            __builtin_amdgcn_global_load_lds(AS1(sb), AS3((char*)Bs + chunk * 1024), 16, 0, 0);
        }
    };

    auto compute = [&]() {
        const int krow = lane >> 4; // 0..3
        const int rl = lane & 15;
#pragma unroll
        for (int kk = 0; kk < 2; ++kk) {
            half8 af[4], bf[4];
#pragma unroll
            for (int m = 0; m < 4; ++m) {
                int r = wm * 64 + m * 16 + rl;
                int kb = (kk * 4 + krow) ^ (r & 7); // XOR de-swizzle on read
                af[m] = *(const half8*)((const char*)As + r * 128 + kb * 16);
            }
#pragma unroll
            for (int n = 0; n < 4; ++n) {
                int r = wn * 64 + n * 16 + rl;
                int kb = (kk * 4 + krow) ^ (r & 7);
                bf[n] = *(const half8*)((const char*)Bs + r * 128 + kb * 16);
            }
#pragma unroll
            for (int m = 0; m < 4; ++m)
#pragma unroll
                for (int n = 0; n < 4; ++n)
                    acc[m][n] = __builtin_amdgcn_mfma_f32_16x16x32_f16(af[m], bf[n], acc[m][n], 0, 0, 0);
        }
    };

    // m97 loop: single buffer, drain hidden by 4 co-resident blocks
#pragma unroll 1
    for (int k0 = 0; k0 < DIM; k0 += 64) {
        stage(k0);
        __syncthreads();
        compute();
        __syncthreads();
    }

    // epilogue
    const float cosM = 0.8775825618903728f;
    const float sinM = 0.4794255386042030f;
    const int col_l = lane & 15;
    const int rgrp = lane >> 4;
    float* buf = (float*)As;   // PASS 1 repack buffer [32][128] f32 (16 KB)

#pragma unroll
    for (int m = 0; m < 4; ++m) {
        int lr0 = wm * 64 + m * 16 + rgrp * 4;   // local row base 0..127
        int gr0 = tileM + lr0;
        float rnv[4]; int labv[4]; float rsv[4];
#pragma unroll
        for (int r = 0; r < 4; ++r) {
            rnv[r] = rn[gr0 + r];
            labv[r] = lab[gr0 + r];
            if (PASS == 1) rsv[r] = rs[gr0 + r];
        }
        float rowacc[4] = {0.f, 0.f, 0.f, 0.f};
#pragma unroll
        for (int n = 0; n < 4; ++n) {
            int gc = tileN + wn * 64 + n * 16 + col_l;
            bool okc = (gc < NCLS);
            float cnv = okc ? cn[gc] : 0.f;
#pragma unroll
            for (int r = 0; r < 4; ++r) {
                float cv = acc[m][n][r] * rnv[r] * cnv;
                float logit;
                if (gc == labv[r]) {
                    float cc = fminf(fmaxf(cv, -1.f + 1e-7f), 1.f - 1e-7f);
                    logit = 64.f * (cc * cosM - sqrtf(1.f - cc * cc) * sinM);
                } else {
                    logit = 64.f * cv;
                }
                float e = __expf(logit);
                if (PASS == 0) {
                    if (okc) rowacc[r] += e;
                } else {
                    // local row (wm*16 + rgrp*4 + r) in 32-row slab, col 0..127
                    buf[(wm * 16 + rgrp * 4 + r) * 128 + wn * 64 + n * 16 + col_l] = e * rsv[r];
                }
            }
        }
        if (PASS == 0) {
#pragma unroll
            for (int r = 0; r < 4; ++r) {
                float s = rowacc[r];
                s += __shfl_xor(s, 1);
                s += __shfl_xor(s, 2);
                s += __shfl_xor(s, 4);
                s += __shfl_xor(s, 8);
                if (col_l == 0) rsum[wn][lr0 + r] = s;
            }
        } else {
            __syncthreads();   // buf slab complete
            // cooperative coalesced float4 store: 32 rows x 128 cols
#pragma unroll
            for (int i = 0; i < 4; ++i) {
                int idx = tid + i * 256;          // 0..1023
                int lr = idx >> 5;                // 0..31
                int c4 = idx & 31;
                int gr = tileM + (lr >> 4) * 64 + m * 16 + (lr & 15);
                int gcl = tileN + c4 * 4;
                if (gcl < NCLS)
                    *(float4*)(out + (size_t)gr * NCLS + gcl) = ((float4*)buf)[idx];
            }
            __syncthreads();   // before next m overwrites buf
        }
    }
    if (PASS == 0) {
        __syncthreads();
        if (tid < 128) {
            float tot = rsum[0][tid] + rsum[1][tid];
            rowpart[(size_t)nt * NROW + tileM + tid] = tot;
        }
    }
}

// ---------------- reduce per-tile row sums -> 1/rowsum ---------------------------
__global__ void reduce_rs_kernel(const float* __restrict__ rowpart, float* __restrict__ rs)
{
    int row = blockIdx.x * 256 + threadIdx.x; // 4 x 256 = 1024
    float s = 0.f;
    for (int t = 0; t < NTN; ++t) s += rowpart[(size_t)t * NROW + row];
    rs[row] = 1.f / s;
}

extern "C" void kernel_launch(void* const* d_in, const int* in_sizes, int n_in,
                              void* d_out, int out_size, void* d_ws, size_t ws_size,
                              hipStream_t stream)
{
    const float* x = (const float*)d_in[0]; // [1024][512]
    const float* y = (const float*)d_in[1]; // [1024][50000] one-hot
    const float* W = (const float*)d_in[2]; // [512][50000]
    float* out = (float*)d_out;             // [1024][50000]

    char* ws = (char*)d_ws;
    __half* Wt     = (__half*)(ws);               // 51,200,000 B : W^T fp16 [50000][512]
    __half* xh     = (__half*)(ws + 51200000);    //  1,048,576 B : x fp16
    float* rn      = (float*) (ws + 52248576);    //      4,096 B : row inv-norms
    float* cn      = (float*) (ws + 52252672);    //    200,000 B : col inv-norms
    // part [8][50000] (consumed by make_cn) then reused as rowpart [391][1024]
    float* part    = (float*) (ws + 52452672);    //  1,601,536 B : union(part, rowpart)
    float* rowpart = part;
    int*   lab     = (int*)   (ws + 54054208);    //      4,096 B : labels
    float* rs      = (float*) (ws + 54058304);    //      4,096 B : 1/rowsum

    hipLaunchKernelGGL(prep_x_kernel, dim3(NROW), dim3(64), 0, stream, x, xh, rn);
    hipLaunchKernelGGL(prep_w_labels_kernel, dim3(6256 + 2048), dim3(256), 0, stream,
                       W, Wt, part, (const float4*)y, lab);
    hipLaunchKernelGGL(make_cn_kernel, dim3(196), dim3(256), 0, stream, part, cn);
    hipLaunchKernelGGL(gemm_arc_kernel<0>, dim3(8 * NTN), dim3(256), 0, stream,
                       xh, Wt, rn, cn, lab, rs, out, rowpart);
    hipLaunchKernelGGL(reduce_rs_kernel, dim3(4), dim3(256), 0, stream, rowpart, rs);
    hipLaunchKernelGGL(gemm_arc_kernel<1>, dim3(8 * NTN), dim3(256), 0, stream,
                       xh, Wt, rn, cn, lab, rs, out, rowpart);
}

// Round 13
// 249.232 us; speedup vs baseline: 1.0686x; 1.0150x over previous
//
#include <hip/hip_runtime.h>
#include <hip/hip_fp16.h>
#include <cstdint>
#include <cstddef>

#define NCLS 50000
#define DIM 512
#define NROW 1024
#define NTN 391   // ceil(50000/128)

typedef _Float16 half8 __attribute__((ext_vector_type(8)));
typedef float f32x4 __attribute__((ext_vector_type(4)));

#define AS1(p) ((const __attribute__((address_space(1))) void*)(p))
#define AS3(p) ((__attribute__((address_space(3))) void*)(p))

// ---- fused: W transpose+fp16 (+col sumsq partials) || y label scan || x prep ----
// Blocks 0..6255        : transpose body (782 n-tiles x 8 k-tiles).
// Blocks 6256..8303     : grid-stride one-hot scan (2048 virtual blocks).
// Blocks 8304..8559     : x -> fp16 + row inv-norms (4 rows per block).
// All three are memory-bound streams sharing one BW window.
__global__ void prep_all_kernel(const float* __restrict__ W,
                                __half* __restrict__ Wt,
                                float* __restrict__ part,
                                const float4* __restrict__ y4,
                                int* __restrict__ lab,
                                const float* __restrict__ x,
                                __half* __restrict__ xh,
                                float* __restrict__ rn)
{
    __shared__ float tile[64][65];
    __shared__ float cpart[4][64];

    const int t = threadIdx.x; // 256
    if (blockIdx.x < 6256) {
        const int bx = blockIdx.x % 782;   // n-tile
        const int by = blockIdx.x / 782;   // k-tile 0..7
        int n0 = bx * 64;
        int k0 = by * 64;
        int f4 = t & 15;
        int kr = t >> 4;
        int n = n0 + f4 * 4;
        bool ok = (n < NCLS);
#pragma unroll
        for (int i = 0; i < 4; ++i) {
            int k = kr + i * 16;
            float4 v = ok ? *(const float4*)(W + (size_t)(k0 + k) * NCLS + n)
                          : make_float4(0.f, 0.f, 0.f, 0.f);
            tile[k][f4 * 4 + 0] = v.x;
            tile[k][f4 * 4 + 1] = v.y;
            tile[k][f4 * 4 + 2] = v.z;
            tile[k][f4 * 4 + 3] = v.w;
        }
        __syncthreads();
#pragma unroll
        for (int i = 0; i < 8; ++i) {
            int idx = t + i * 256;
            int nn = idx >> 5;
            int kp = idx & 31;
            int gn = n0 + nn;
            if (gn < NCLS) {
                __half2 h = __floats2half2_rn(tile[kp * 2][nn], tile[kp * 2 + 1][nn]);
                *(__half2*)(Wt + (size_t)gn * DIM + k0 + kp * 2) = h;
            }
        }
        {
            int nn = t & 63;
            int seg = t >> 6;
            float s = 0.f;
#pragma unroll
            for (int k = 0; k < 16; ++k) {
                float v = tile[seg * 16 + k][nn];
                s += v * v;
            }
            cpart[seg][nn] = s;
            __syncthreads();
            if (t < 64 && n0 + t < NCLS) {
                part[(size_t)by * NCLS + n0 + t] =
                    cpart[0][t] + cpart[1][t] + cpart[2][t] + cpart[3][t];
            }
        }
    } else if (blockIdx.x < 8304) {
        // grid-stride label scan: 2048 vblocks x 256 threads over 12.8M float4
        const int vb = blockIdx.x - 6256;
        for (int i4 = vb * 256 + t; i4 < 12800000; i4 += 2048 * 256) {
            float4 v = y4[i4];
            if (v.x != 0.f || v.y != 0.f || v.z != 0.f || v.w != 0.f) {
                long base = (long)i4 * 4;
                if (v.x != 0.f) { long i = base + 0; lab[i / NCLS] = (int)(i % NCLS); }
                if (v.y != 0.f) { long i = base + 1; lab[i / NCLS] = (int)(i % NCLS); }
                if (v.z != 0.f) { long i = base + 2; lab[i / NCLS] = (int)(i % NCLS); }
                if (v.w != 0.f) { long i = base + 3; lab[i / NCLS] = (int)(i % NCLS); }
            }
        }
    } else {
        // x prep: 4 rows per block (one wave per row)
        int row = (blockIdx.x - 8304) * 4 + (t >> 6);
        int l = t & 63;
        const float4* xr = (const float4*)(x + (size_t)row * DIM);
        __half2* dst = (__half2*)(xh + (size_t)row * DIM);
        float s = 0.f;
#pragma unroll
        for (int i = 0; i < 2; ++i) {
            int idx = l + i * 64;
            float4 v = xr[idx];
            dst[idx * 2]     = __floats2half2_rn(v.x, v.y);
            dst[idx * 2 + 1] = __floats2half2_rn(v.z, v.w);
            s += v.x * v.x + v.y * v.y + v.z * v.z + v.w * v.w;
        }
#pragma unroll
        for (int off = 32; off > 0; off >>= 1) s += __shfl_down(s, off);
        if (l == 0) rn[row] = rsqrtf(s);
    }
}

__global__ void make_cn_kernel(const float* __restrict__ part, float* __restrict__ cn)
{
    int c = blockIdx.x * 256 + threadIdx.x;
    if (c >= NCLS) return;
    float s = 0.f;
#pragma unroll
    for (int j = 0; j < 8; ++j) s += part[(size_t)j * NCLS + c];
    cn[c] = rsqrtf(s);
}

// ---------------- GEMM + arcface + exp, two-pass (r9/r12 champion) ---------------
// m97 structure: 128x128 tile, BK=64, 4 waves (2x2), single 32 KB LDS buffer,
// stage->sync->compute->sync, 4 blocks/CU.
// PASS 0: margin via lab[]; writes rowpart sums only (forward nt order).
// PASS 1: margin via lab[]; e*rs via LDS repack (REVERSED nt order for L3 reuse).
template<int PASS>
__global__ __launch_bounds__(256, 4) void gemm_arc_kernel(
    const __half* __restrict__ A,
    const __half* __restrict__ Bt,
    const float* __restrict__ rn,
    const float* __restrict__ cn,
    const int* __restrict__ lab,
    const float* __restrict__ rs,
    float* __restrict__ out,
    float* __restrict__ rowpart)
{
    __shared__ __align__(16) __half As[128 * 64];
    __shared__ __align__(16) __half Bs[128 * 64];
    __shared__ float rsum[2][128];

    const int tid = threadIdx.x;
    const int wid = tid >> 6;
    const int lane = tid & 63;
    const int wm = wid >> 1;
    const int wn = wid & 1;

    // bijective XCD swizzle: 3128 = 8 * 391; M-fastest (8 mt per nt) for Bt reuse
    const int b = blockIdx.x;
    const int w = (b & 7) * NTN + (b >> 3);
    const int mt = w & 7;
    const int nt0 = w >> 3;
    const int nt = (PASS == 1) ? (NTN - 1 - nt0) : nt0;  // pass 1 walks panels backwards
    const int tileM = mt * 128;
    const int tileN = nt * 128;

    const int srow = lane >> 3;            // 0..7
    const int sblk = (lane & 7) ^ srow;    // pre-swizzled global 16B-block

    f32x4 acc[4][4] = {};

    auto stage = [&](int k0) {
#pragma unroll
        for (int c = 0; c < 4; ++c) {
            int chunk = wid * 4 + c;       // wave-uniform
            int row = chunk * 8 + srow;    // 0..127
            const __half* sa = A + (size_t)(tileM + row) * DIM + k0 + sblk * 8;
            __builtin_amdgcn_global_load_lds(AS1(sa), AS3((char*)As + chunk * 1024), 16, 0, 0);
            int gn = tileN + row;
            if (gn > NCLS - 1) gn = NCLS - 1; // clamp N edge (masked later)
            const __half* sb = Bt + (size_t)gn * DIM + k0 + sblk * 8;
            __builtin_amdgcn_global_load_lds(AS1(sb), AS3((char*)Bs + chunk * 1024), 16, 0, 0);
        }
    };

    auto compute = [&]() {
        const int krow = lane >> 4; // 0..3
        const int rl = lane & 15;
#pragma unroll
        for (int kk = 0; kk < 2; ++kk) {
            half8 af[4], bf[4];
#pragma unroll
            for (int m = 0; m < 4; ++m) {
                int r = wm * 64 + m * 16 + rl;
                int kb = (kk * 4 + krow) ^ (r & 7); // XOR de-swizzle on read
                af[m] = *(const half8*)((const char*)As + r * 128 + kb * 16);
            }
#pragma unroll
            for (int n = 0; n < 4; ++n) {
                int r = wn * 64 + n * 16 + rl;
                int kb = (kk * 4 + krow) ^ (r & 7);
                bf[n] = *(const half8*)((const char*)Bs + r * 128 + kb * 16);
            }
#pragma unroll
            for (int m = 0; m < 4; ++m)
#pragma unroll
                for (int n = 0; n < 4; ++n)
                    acc[m][n] = __builtin_amdgcn_mfma_f32_16x16x32_f16(af[m], bf[n], acc[m][n], 0, 0, 0);
        }
    };

    // m97 loop: single buffer, drain hidden by 4 co-resident blocks
#pragma unroll 1
    for (int k0 = 0; k0 < DIM; k0 += 64) {
        stage(k0);
        __syncthreads();
        compute();
        __syncthreads();
    }

    // epilogue
    const float cosM = 0.8775825618903728f;
    const float sinM = 0.4794255386042030f;
    const int col_l = lane & 15;
    const int rgrp = lane >> 4;
    float* buf = (float*)As;   // PASS 1 repack buffer [32][128] f32 (16 KB)

#pragma unroll
    for (int m = 0; m < 4; ++m) {
        int lr0 = wm * 64 + m * 16 + rgrp * 4;   // local row base 0..127
        int gr0 = tileM + lr0;
        float rnv[4]; int labv[4]; float rsv[4];
#pragma unroll
        for (int r = 0; r < 4; ++r) {
            rnv[r] = rn[gr0 + r];
            labv[r] = lab[gr0 + r];
            if (PASS == 1) rsv[r] = rs[gr0 + r];
        }
        float rowacc[4] = {0.f, 0.f, 0.f, 0.f};
#pragma unroll
        for (int n = 0; n < 4; ++n) {
            int gc = tileN + wn * 64 + n * 16 + col_l;
            bool okc = (gc < NCLS);
            float cnv = okc ? cn[gc] : 0.f;
#pragma unroll
            for (int r = 0; r < 4; ++r) {
                float cv = acc[m][n][r] * rnv[r] * cnv;
                float logit;
                if (gc == labv[r]) {
                    float cc = fminf(fmaxf(cv, -1.f + 1e-7f), 1.f - 1e-7f);
                    logit = 64.f * (cc * cosM - sqrtf(1.f - cc * cc) * sinM);
                } else {
                    logit = 64.f * cv;
                }
                float e = __expf(logit);
                if (PASS == 0) {
                    if (okc) rowacc[r] += e;
                } else {
                    buf[(wm * 16 + rgrp * 4 + r) * 128 + wn * 64 + n * 16 + col_l] = e * rsv[r];
                }
            }
        }
        if (PASS == 0) {
#pragma unroll
            for (int r = 0; r < 4; ++r) {
                float s = rowacc[r];
                s += __shfl_xor(s, 1);
                s += __shfl_xor(s, 2);
                s += __shfl_xor(s, 4);
                s += __shfl_xor(s, 8);
                if (col_l == 0) rsum[wn][lr0 + r] = s;
            }
        } else {
            __syncthreads();   // buf slab complete
            // cooperative coalesced float4 store: 32 rows x 128 cols
#pragma unroll
            for (int i = 0; i < 4; ++i) {
                int idx = tid + i * 256;          // 0..1023
                int lr = idx >> 5;                // 0..31
                int c4 = idx & 31;
                int gr = tileM + (lr >> 4) * 64 + m * 16 + (lr & 15);
                int gcl = tileN + c4 * 4;
                if (gcl < NCLS)
                    *(float4*)(out + (size_t)gr * NCLS + gcl) = ((float4*)buf)[idx];
            }
            __syncthreads();   // before next m overwrites buf
        }
    }
    if (PASS == 0) {
        __syncthreads();
        if (tid < 128) {
            float tot = rsum[0][tid] + rsum[1][tid];
            rowpart[(size_t)nt * NROW + tileM + tid] = tot;
        }
    }
}

// ---------------- reduce per-tile row sums -> 1/rowsum ---------------------------
__global__ void reduce_rs_kernel(const float* __restrict__ rowpart, float* __restrict__ rs)
{
    int row = blockIdx.x * 256 + threadIdx.x; // 4 x 256 = 1024
    float s = 0.f;
    for (int t = 0; t < NTN; ++t) s += rowpart[(size_t)t * NROW + row];
    rs[row] = 1.f / s;
}

extern "C" void kernel_launch(void* const* d_in, const int* in_sizes, int n_in,
                              void* d_out, int out_size, void* d_ws, size_t ws_size,
                              hipStream_t stream)
{
    const float* x = (const float*)d_in[0]; // [1024][512]
    const float* y = (const float*)d_in[1]; // [1024][50000] one-hot
    const float* W = (const float*)d_in[2]; // [512][50000]
    float* out = (float*)d_out;             // [1024][50000]

    char* ws = (char*)d_ws;
    __half* Wt     = (__half*)(ws);               // 51,200,000 B : W^T fp16 [50000][512]
    __half* xh     = (__half*)(ws + 51200000);    //  1,048,576 B : x fp16
    float* rn      = (float*) (ws + 52248576);    //      4,096 B : row inv-norms
    float* cn      = (float*) (ws + 52252672);    //    200,000 B : col inv-norms
    // part [8][50000] (consumed by make_cn) then reused as rowpart [391][1024]
    float* part    = (float*) (ws + 52452672);    //  1,601,536 B : union(part, rowpart)
    float* rowpart = part;
    int*   lab     = (int*)   (ws + 54054208);    //      4,096 B : labels
    float* rs      = (float*) (ws + 54058304);    //      4,096 B : 1/rowsum

    hipLaunchKernelGGL(prep_all_kernel, dim3(6256 + 2048 + 256), dim3(256), 0, stream,
                       W, Wt, part, (const float4*)y, lab, x, xh, rn);
    hipLaunchKernelGGL(make_cn_kernel, dim3(196), dim3(256), 0, stream, part, cn);
    hipLaunchKernelGGL(gemm_arc_kernel<0>, dim3(8 * NTN), dim3(256), 0, stream,
                       xh, Wt, rn, cn, lab, rs, out, rowpart);
    hipLaunchKernelGGL(reduce_rs_kernel, dim3(4), dim3(256), 0, stream, rowpart, rs);
    hipLaunchKernelGGL(gemm_arc_kernel<1>, dim3(8 * NTN), dim3(256), 0, stream,
                       xh, Wt, rn, cn, lab, rs, out, rowpart);
}

// Round 14
// 246.617 us; speedup vs baseline: 1.0800x; 1.0106x over previous
//
#include <hip/hip_runtime.h>
#include <hip/hip_fp16.h>
#include <cstdint>
#include <cstddef>

#define NCLS 50000
#define DIM 512
#define NROW 1024
#define NTN 391   // ceil(50000/128)

typedef _Float16 half8 __attribute__((ext_vector_type(8)));
typedef float f32x4 __attribute__((ext_vector_type(4)));
typedef unsigned short us4 __attribute__((ext_vector_type(4)));
typedef unsigned short us8 __attribute__((ext_vector_type(8)));

#define AS1(p) ((const __attribute__((address_space(1))) void*)(p))
#define AS3(p) ((__attribute__((address_space(3))) void*)(p))

// ---- fused: W transpose+fp16 (+col sumsq partials) || y label scan || x prep ----
__global__ void prep_all_kernel(const float* __restrict__ W,
                                __half* __restrict__ Wt,
                                float* __restrict__ part,
                                const float4* __restrict__ y4,
                                int* __restrict__ lab,
                                const float* __restrict__ x,
                                __half* __restrict__ xh,
                                float* __restrict__ rn)
{
    __shared__ float tile[64][65];
    __shared__ float cpart[4][64];

    const int t = threadIdx.x; // 256
    if (blockIdx.x < 6256) {
        const int bx = blockIdx.x % 782;   // n-tile
        const int by = blockIdx.x / 782;   // k-tile 0..7
        int n0 = bx * 64;
        int k0 = by * 64;
        int f4 = t & 15;
        int kr = t >> 4;
        int n = n0 + f4 * 4;
        bool ok = (n < NCLS);
#pragma unroll
        for (int i = 0; i < 4; ++i) {
            int k = kr + i * 16;
            float4 v = ok ? *(const float4*)(W + (size_t)(k0 + k) * NCLS + n)
                          : make_float4(0.f, 0.f, 0.f, 0.f);
            tile[k][f4 * 4 + 0] = v.x;
            tile[k][f4 * 4 + 1] = v.y;
            tile[k][f4 * 4 + 2] = v.z;
            tile[k][f4 * 4 + 3] = v.w;
        }
        __syncthreads();
#pragma unroll
        for (int i = 0; i < 8; ++i) {
            int idx = t + i * 256;
            int nn = idx >> 5;
            int kp = idx & 31;
            int gn = n0 + nn;
            if (gn < NCLS) {
                __half2 h = __floats2half2_rn(tile[kp * 2][nn], tile[kp * 2 + 1][nn]);
                *(__half2*)(Wt + (size_t)gn * DIM + k0 + kp * 2) = h;
            }
        }
        {
            int nn = t & 63;
            int seg = t >> 6;
            float s = 0.f;
#pragma unroll
            for (int k = 0; k < 16; ++k) {
                float v = tile[seg * 16 + k][nn];
                s += v * v;
            }
            cpart[seg][nn] = s;
            __syncthreads();
            if (t < 64 && n0 + t < NCLS) {
                part[(size_t)by * NCLS + n0 + t] =
                    cpart[0][t] + cpart[1][t] + cpart[2][t] + cpart[3][t];
            }
        }
    } else if (blockIdx.x < 8304) {
        const int vb = blockIdx.x - 6256;
        for (int i4 = vb * 256 + t; i4 < 12800000; i4 += 2048 * 256) {
            float4 v = y4[i4];
            if (v.x != 0.f || v.y != 0.f || v.z != 0.f || v.w != 0.f) {
                long base = (long)i4 * 4;
                if (v.x != 0.f) { long i = base + 0; lab[i / NCLS] = (int)(i % NCLS); }
                if (v.y != 0.f) { long i = base + 1; lab[i / NCLS] = (int)(i % NCLS); }
                if (v.z != 0.f) { long i = base + 2; lab[i / NCLS] = (int)(i % NCLS); }
                if (v.w != 0.f) { long i = base + 3; lab[i / NCLS] = (int)(i % NCLS); }
            }
        }
    } else {
        int row = (blockIdx.x - 8304) * 4 + (t >> 6);
        int l = t & 63;
        const float4* xr = (const float4*)(x + (size_t)row * DIM);
        __half2* dst = (__half2*)(xh + (size_t)row * DIM);
        float s = 0.f;
#pragma unroll
        for (int i = 0; i < 2; ++i) {
            int idx = l + i * 64;
            float4 v = xr[idx];
            dst[idx * 2]     = __floats2half2_rn(v.x, v.y);
            dst[idx * 2 + 1] = __floats2half2_rn(v.z, v.w);
            s += v.x * v.x + v.y * v.y + v.z * v.z + v.w * v.w;
        }
#pragma unroll
        for (int off = 32; off > 0; off >>= 1) s += __shfl_down(s, off);
        if (l == 0) rn[row] = rsqrtf(s);
    }
}

__global__ void make_cn_kernel(const float* __restrict__ part, float* __restrict__ cn)
{
    int c = blockIdx.x * 256 + threadIdx.x;
    if (c >= NCLS) return;
    float s = 0.f;
#pragma unroll
    for (int j = 0; j < 8; ++j) s += part[(size_t)j * NCLS + c];
    cn[c] = rsqrtf(s);
}

// ======================= PRIMARY PATH: single GEMM + bf16 e =====================
// m97 structure, 128x128, 4 waves, 4 blocks/CU. Computes e=exp(logit), rounds to
// bf16 (restores num/denom cancellation), accumulates row sums from the ROUNDED
// value, stores bf16 e to eh via LDS repack. finalize scales eh*rs -> f32 out.
__global__ __launch_bounds__(256, 4) void gemm_arc_e_kernel(
    const __half* __restrict__ A,
    const __half* __restrict__ Bt,
    const float* __restrict__ rn,
    const float* __restrict__ cn,
    const int* __restrict__ lab,
    unsigned short* __restrict__ eh,
    float* __restrict__ rowpart)
{
    __shared__ __align__(16) __half As[128 * 64];
    __shared__ __align__(16) __half Bs[128 * 64];
    __shared__ float rsum[2][128];

    const int tid = threadIdx.x;
    const int wid = tid >> 6;
    const int lane = tid & 63;
    const int wm = wid >> 1;
    const int wn = wid & 1;

    const int b = blockIdx.x;
    const int w = (b & 7) * NTN + (b >> 3);
    const int mt = w & 7;
    const int nt = w >> 3;
    const int tileM = mt * 128;
    const int tileN = nt * 128;

    const int srow = lane >> 3;
    const int sblk = (lane & 7) ^ srow;

    f32x4 acc[4][4] = {};

    auto stage = [&](int k0) {
#pragma unroll
        for (int c = 0; c < 4; ++c) {
            int chunk = wid * 4 + c;
            int row = chunk * 8 + srow;
            const __half* sa = A + (size_t)(tileM + row) * DIM + k0 + sblk * 8;
            __builtin_amdgcn_global_load_lds(AS1(sa), AS3((char*)As + chunk * 1024), 16, 0, 0);
            int gn = tileN + row;
            if (gn > NCLS - 1) gn = NCLS - 1;
            const __half* sb = Bt + (size_t)gn * DIM + k0 + sblk * 8;
            __builtin_amdgcn_global_load_lds(AS1(sb), AS3((char*)Bs + chunk * 1024), 16, 0, 0);
        }
    };

    auto compute = [&]() {
        const int krow = lane >> 4;
        const int rl = lane & 15;
#pragma unroll
        for (int kk = 0; kk < 2; ++kk) {
            half8 af[4], bf[4];
#pragma unroll
            for (int m = 0; m < 4; ++m) {
                int r = wm * 64 + m * 16 + rl;
                int kb = (kk * 4 + krow) ^ (r & 7);
                af[m] = *(const half8*)((const char*)As + r * 128 + kb * 16);
            }
#pragma unroll
            for (int n = 0; n < 4; ++n) {
                int r = wn * 64 + n * 16 + rl;
                int kb = (kk * 4 + krow) ^ (r & 7);
                bf[n] = *(const half8*)((const char*)Bs + r * 128 + kb * 16);
            }
#pragma unroll
            for (int m = 0; m < 4; ++m)
#pragma unroll
                for (int n = 0; n < 4; ++n)
                    acc[m][n] = __builtin_amdgcn_mfma_f32_16x16x32_f16(af[m], bf[n], acc[m][n], 0, 0, 0);
        }
    };

#pragma unroll 1
    for (int k0 = 0; k0 < DIM; k0 += 64) {
        stage(k0);
        __syncthreads();
        compute();
        __syncthreads();
    }

    const float cosM = 0.8775825618903728f;
    const float sinM = 0.4794255386042030f;
    const int col_l = lane & 15;
    const int rgrp = lane >> 4;
    float* buf = (float*)As;   // repack buffer [32][128] f32 (16 KB)

#pragma unroll
    for (int m = 0; m < 4; ++m) {
        int lr0 = wm * 64 + m * 16 + rgrp * 4;
        int gr0 = tileM + lr0;
        float rnv[4]; int labv[4];
#pragma unroll
        for (int r = 0; r < 4; ++r) {
            rnv[r] = rn[gr0 + r];
            labv[r] = lab[gr0 + r];
        }
        float rowacc[4] = {0.f, 0.f, 0.f, 0.f};
#pragma unroll
        for (int n = 0; n < 4; ++n) {
            int gc = tileN + wn * 64 + n * 16 + col_l;
            bool okc = (gc < NCLS);
            float cnv = okc ? cn[gc] : 0.f;
#pragma unroll
            for (int r = 0; r < 4; ++r) {
                float cv = acc[m][n][r] * rnv[r] * cnv;
                float logit;
                if (gc == labv[r]) {
                    float cc = fminf(fmaxf(cv, -1.f + 1e-7f), 1.f - 1e-7f);
                    logit = 64.f * (cc * cosM - sqrtf(1.f - cc * cc) * sinM);
                } else {
                    logit = 64.f * cv;
                }
                float e = __expf(logit);
                // round-to-nearest-even to bf16, keep as f32 (low mantissa zero)
                unsigned int u = __float_as_uint(e);
                u += 0x7FFFu + ((u >> 16) & 1u);
                float ef = __uint_as_float(u & 0xFFFF0000u);
                if (okc) rowacc[r] += ef;
                buf[(wm * 16 + rgrp * 4 + r) * 128 + wn * 64 + n * 16 + col_l] = ef;
            }
        }
#pragma unroll
        for (int r = 0; r < 4; ++r) {
            float s = rowacc[r];
            s += __shfl_xor(s, 1);
            s += __shfl_xor(s, 2);
            s += __shfl_xor(s, 4);
            s += __shfl_xor(s, 8);
            if (col_l == 0) rsum[wn][lr0 + r] = s;
        }
        __syncthreads();   // buf slab complete
        // bf16 store: 1024 groups of 4 elems (8 B each), coalesced 256 B segments
#pragma unroll
        for (int i = 0; i < 4; ++i) {
            int idx = tid + i * 256;          // 0..1023
            int lr = idx >> 5;                // 0..31
            int c4 = idx & 31;
            int gr = tileM + (lr >> 4) * 64 + m * 16 + (lr & 15);
            int gcl = tileN + c4 * 4;
            if (gcl < NCLS) {
                f32x4 v = ((const f32x4*)buf)[idx];
                us4 o;
                o[0] = (unsigned short)(__float_as_uint(v[0]) >> 16);
                o[1] = (unsigned short)(__float_as_uint(v[1]) >> 16);
                o[2] = (unsigned short)(__float_as_uint(v[2]) >> 16);
                o[3] = (unsigned short)(__float_as_uint(v[3]) >> 16);
                *(us4*)(eh + (size_t)gr * NCLS + gcl) = o;
            }
        }
        __syncthreads();   // before next m overwrites buf
    }
    if (tid < 128) {
        float tot = rsum[0][tid] + rsum[1][tid];
        rowpart[(size_t)nt * NROW + tileM + tid] = tot;
    }
}

// ---------------- eh (bf16) * rs -> out (f32), streaming ------------------------
__global__ void finalize_e_kernel(const unsigned short* __restrict__ eh,
                                  const float* __restrict__ rs,
                                  float* __restrict__ out)
{
    int row = blockIdx.y;
    int i = blockIdx.x * 256 + threadIdx.x;   // ushort8 group, 6250 per row
    if (i < 6250) {
        float s = rs[row];
        us8 v = *(const us8*)(eh + (size_t)row * NCLS + i * 8);
        float4 o0, o1;
        o0.x = __uint_as_float((unsigned int)v[0] << 16) * s;
        o0.y = __uint_as_float((unsigned int)v[1] << 16) * s;
        o0.z = __uint_as_float((unsigned int)v[2] << 16) * s;
        o0.w = __uint_as_float((unsigned int)v[3] << 16) * s;
        o1.x = __uint_as_float((unsigned int)v[4] << 16) * s;
        o1.y = __uint_as_float((unsigned int)v[5] << 16) * s;
        o1.z = __uint_as_float((unsigned int)v[6] << 16) * s;
        o1.w = __uint_as_float((unsigned int)v[7] << 16) * s;
        float* p = out + (size_t)row * NCLS + i * 8;
        *(float4*)p = o0;
        *(float4*)(p + 4) = o1;
    }
}

// ======================= FALLBACK PATH: r13 two-pass (verbatim) ==================
template<int PASS>
__global__ __launch_bounds__(256, 4) void gemm_arc_kernel(
    const __half* __restrict__ A,
    const __half* __restrict__ Bt,
    const float* __restrict__ rn,
    const float* __restrict__ cn,
    const int* __restrict__ lab,
    const float* __restrict__ rs,
    float* __restrict__ out,
    float* __restrict__ rowpart)
{
    __shared__ __align__(16) __half As[128 * 64];
    __shared__ __align__(16) __half Bs[128 * 64];
    __shared__ float rsum[2][128];

    const int tid = threadIdx.x;
    const int wid = tid >> 6;
    const int lane = tid & 63;
    const int wm = wid >> 1;
    const int wn = wid & 1;

    const int b = blockIdx.x;
    const int w = (b & 7) * NTN + (b >> 3);
    const int mt = w & 7;
    const int nt0 = w >> 3;
    const int nt = (PASS == 1) ? (NTN - 1 - nt0) : nt0;
    const int tileM = mt * 128;
    const int tileN = nt * 128;

    const int srow = lane >> 3;
    const int sblk = (lane & 7) ^ srow;

    f32x4 acc[4][4] = {};

    auto stage = [&](int k0) {
#pragma unroll
        for (int c = 0; c < 4; ++c) {
            int chunk = wid * 4 + c;
            int row = chunk * 8 + srow;
            const __half* sa = A + (size_t)(tileM + row) * DIM + k0 + sblk * 8;
            __builtin_amdgcn_global_load_lds(AS1(sa), AS3((char*)As + chunk * 1024), 16, 0, 0);
            int gn = tileN + row;
            if (gn > NCLS - 1) gn = NCLS - 1;
            const __half* sb = Bt + (size_t)gn * DIM + k0 + sblk * 8;
            __builtin_amdgcn_global_load_lds(AS1(sb), AS3((char*)Bs + chunk * 1024), 16, 0, 0);
        }
    };

    auto compute = [&]() {
        const int krow = lane >> 4;
        const int rl = lane & 15;
#pragma unroll
        for (int kk = 0; kk < 2; ++kk) {
            half8 af[4], bf[4];
#pragma unroll
            for (int m = 0; m < 4; ++m) {
                int r = wm * 64 + m * 16 + rl;
                int kb = (kk * 4 + krow) ^ (r & 7);
                af[m] = *(const half8*)((const char*)As + r * 128 + kb * 16);
            }
#pragma unroll
            for (int n = 0; n < 4; ++n) {
                int r = wn * 64 + n * 16 + rl;
                int kb = (kk * 4 + krow) ^ (r & 7);
                bf[n] = *(const half8*)((const char*)Bs + r * 128 + kb * 16);
            }
#pragma unroll
            for (int m = 0; m < 4; ++m)
#pragma unroll
                for (int n = 0; n < 4; ++n)
                    acc[m][n] = __builtin_amdgcn_mfma_f32_16x16x32_f16(af[m], bf[n], acc[m][n], 0, 0, 0);
        }
    };

#pragma unroll 1
    for (int k0 = 0; k0 < DIM; k0 += 64) {
        stage(k0);
        __syncthreads();
        compute();
        __syncthreads();
    }

    const float cosM = 0.8775825618903728f;
    const float sinM = 0.4794255386042030f;
    const int col_l = lane & 15;
    const int rgrp = lane >> 4;
    float* buf = (float*)As;

#pragma unroll
    for (int m = 0; m < 4; ++m) {
        int lr0 = wm * 64 + m * 16 + rgrp * 4;
        int gr0 = tileM + lr0;
        float rnv[4]; int labv[4]; float rsv[4];
#pragma unroll
        for (int r = 0; r < 4; ++r) {
            rnv[r] = rn[gr0 + r];
            labv[r] = lab[gr0 + r];
            if (PASS == 1) rsv[r] = rs[gr0 + r];
        }
        float rowacc[4] = {0.f, 0.f, 0.f, 0.f};
#pragma unroll
        for (int n = 0; n < 4; ++n) {
            int gc = tileN + wn * 64 + n * 16 + col_l;
            bool okc = (gc < NCLS);
            float cnv = okc ? cn[gc] : 0.f;
#pragma unroll
            for (int r = 0; r < 4; ++r) {
                float cv = acc[m][n][r] * rnv[r] * cnv;
                float logit;
                if (gc == labv[r]) {
                    float cc = fminf(fmaxf(cv, -1.f + 1e-7f), 1.f - 1e-7f);
                    logit = 64.f * (cc * cosM - sqrtf(1.f - cc * cc) * sinM);
                } else {
                    logit = 64.f * cv;
                }
                float e = __expf(logit);
                if (PASS == 0) {
                    if (okc) rowacc[r] += e;
                } else {
                    buf[(wm * 16 + rgrp * 4 + r) * 128 + wn * 64 + n * 16 + col_l] = e * rsv[r];
                }
            }
        }
        if (PASS == 0) {
#pragma unroll
            for (int r = 0; r < 4; ++r) {
                float s = rowacc[r];
                s += __shfl_xor(s, 1);
                s += __shfl_xor(s, 2);
                s += __shfl_xor(s, 4);
                s += __shfl_xor(s, 8);
                if (col_l == 0) rsum[wn][lr0 + r] = s;
            }
        } else {
            __syncthreads();
#pragma unroll
            for (int i = 0; i < 4; ++i) {
                int idx = tid + i * 256;
                int lr = idx >> 5;
                int c4 = idx & 31;
                int gr = tileM + (lr >> 4) * 64 + m * 16 + (lr & 15);
                int gcl = tileN + c4 * 4;
                if (gcl < NCLS)
                    *(float4*)(out + (size_t)gr * NCLS + gcl) = ((float4*)buf)[idx];
            }
            __syncthreads();
        }
    }
    if (PASS == 0) {
        __syncthreads();
        if (tid < 128) {
            float tot = rsum[0][tid] + rsum[1][tid];
            rowpart[(size_t)nt * NROW + tileM + tid] = tot;
        }
    }
}

// ---------------- reduce per-tile row sums -> 1/rowsum ---------------------------
__global__ void reduce_rs_kernel(const float* __restrict__ rowpart, float* __restrict__ rs)
{
    int row = blockIdx.x * 256 + threadIdx.x;
    float s = 0.f;
    for (int t = 0; t < NTN; ++t) s += rowpart[(size_t)t * NROW + row];
    rs[row] = 1.f / s;
}

extern "C" void kernel_launch(void* const* d_in, const int* in_sizes, int n_in,
                              void* d_out, int out_size, void* d_ws, size_t ws_size,
                              hipStream_t stream)
{
    const float* x = (const float*)d_in[0]; // [1024][512]
    const float* y = (const float*)d_in[1]; // [1024][50000] one-hot
    const float* W = (const float*)d_in[2]; // [512][50000]
    float* out = (float*)d_out;             // [1024][50000]

    char* ws = (char*)d_ws;
    __half* Wt     = (__half*)(ws);               // 51,200,000 B : W^T fp16 [50000][512]
    __half* xh     = (__half*)(ws + 51200000);    //  1,048,576 B : x fp16
    float* rn      = (float*) (ws + 52248576);    //      4,096 B : row inv-norms
    float* cn      = (float*) (ws + 52252672);    //    200,000 B : col inv-norms
    float* part    = (float*) (ws + 52452672);    //  1,601,536 B : union(part, rowpart)
    float* rowpart = part;
    int*   lab     = (int*)   (ws + 54054208);    //      4,096 B : labels
    float* rs      = (float*) (ws + 54058304);    //      4,096 B : 1/rowsum
    unsigned short* eh = (unsigned short*)(ws + 54062400); // 102,400,000 B : bf16 e

    const size_t need = 54062400ull + 102400000ull;   // 156,462,400 B

    hipLaunchKernelGGL(prep_all_kernel, dim3(6256 + 2048 + 256), dim3(256), 0, stream,
                       W, Wt, part, (const float4*)y, lab, x, xh, rn);
    hipLaunchKernelGGL(make_cn_kernel, dim3(196), dim3(256), 0, stream, part, cn);

    if (ws_size >= need) {
        // primary: single GEMM writing bf16 e, then streaming finalize
        hipLaunchKernelGGL(gemm_arc_e_kernel, dim3(8 * NTN), dim3(256), 0, stream,
                           xh, Wt, rn, cn, lab, eh, rowpart);
        hipLaunchKernelGGL(reduce_rs_kernel, dim3(4), dim3(256), 0, stream, rowpart, rs);
        hipLaunchKernelGGL(finalize_e_kernel, dim3(25, NROW), dim3(256), 0, stream,
                           eh, rs, out);
    } else {
        // fallback: r13 two-pass recompute
        hipLaunchKernelGGL(gemm_arc_kernel<0>, dim3(8 * NTN), dim3(256), 0, stream,
                           xh, Wt, rn, cn, lab, rs, out, rowpart);
        hipLaunchKernelGGL(reduce_rs_kernel, dim3(4), dim3(256), 0, stream, rowpart, rs);
        hipLaunchKernelGGL(gemm_arc_kernel<1>, dim3(8 * NTN), dim3(256), 0, stream,
                           xh, Wt, rn, cn, lab, rs, out, rowpart);
    }
}